// Round 1
// baseline (1621.712 us; speedup 1.0000x reference)
//
#include <hip/hip_runtime.h>

#define F_IN 128
#define C_DIM 300
#define NEG_SLOPE 0.2f

// ---------- monotone float<->uint mapping for atomicMax on floats ----------
__device__ inline unsigned f2key(float f) {
    unsigned u = __float_as_uint(f);
    return (u & 0x80000000u) ? ~u : (u | 0x80000000u);
}
__device__ inline float key2f(unsigned k) {
    unsigned u = (k & 0x80000000u) ? (k & 0x7FFFFFFFu) : ~k;
    return __uint_as_float(u);
}

// ---------- K1: xl = x@Wl + bl ; xr = x@Wr + br (fused) ----------
// grid: (ceil(C/64), ceil(n/32)), block 256 = (64 cols) x (4 row-groups of 8)
__global__ __launch_bounds__(256) void gemm_xlxr(
    const float* __restrict__ x, const float* __restrict__ Wl,
    const float* __restrict__ bl, const float* __restrict__ Wr,
    const float* __restrict__ br, float* __restrict__ xl,
    float* __restrict__ xr, int n)
{
    __shared__ __align__(16) float xs[32][F_IN];   // 16 KB
    const int row0 = blockIdx.y * 32;
    const int cb   = blockIdx.x * 64;
    const int t    = threadIdx.x;

    // cooperative load: 32 rows x 128 cols = 4096 floats, 4x float4 per thread
    #pragma unroll
    for (int i = 0; i < 4; ++i) {
        int idx = (i * 256 + t) * 4;       // flat float index
        int r = idx >> 7;                   // /128
        int k = idx & 127;
        int gr = row0 + r;
        if (gr >= n) gr = n - 1;            // clamp (row0 < n always)
        *reinterpret_cast<float4*>(&xs[r][k]) =
            *reinterpret_cast<const float4*>(x + (size_t)gr * F_IN + k);
    }
    __syncthreads();

    const int tx = t & 63;                  // col within tile
    const int ty = t >> 6;                  // row group (wave-uniform)
    const int c  = cb + tx;
    if (c >= C_DIM) return;                 // no further barriers

    float accl[8], accr[8];
    #pragma unroll
    for (int i = 0; i < 8; ++i) { accl[i] = 0.f; accr[i] = 0.f; }

    const float* wlp = Wl + c;
    const float* wrp = Wr + c;
    #pragma unroll 4
    for (int k = 0; k < F_IN; ++k) {
        float wl = wlp[(size_t)k * C_DIM];  // coalesced across tx, L2-hot
        float wr = wrp[(size_t)k * C_DIM];
        #pragma unroll
        for (int i = 0; i < 8; ++i) {
            float xv = xs[ty * 8 + i][k];   // wave-broadcast LDS read
            accl[i] = fmaf(xv, wl, accl[i]);
            accr[i] = fmaf(xv, wr, accr[i]);
        }
    }
    const float blv = bl[c], brv = br[c];
    #pragma unroll
    for (int i = 0; i < 8; ++i) {
        int r = row0 + ty * 8 + i;
        if (r < n) {
            xl[(size_t)r * C_DIM + c] = accl[i] + blv;
            xr[(size_t)r * C_DIM + c] = accr[i] + brv;
        }
    }
}

// ---------- K2: per-edge attention logit e_j = att . leaky_relu(xl[s]+xr[d]) ----------
// one wave per edge; edges [0,nE) from edge_index, [nE, nE+n) are self loops
__global__ __launch_bounds__(256) void edge_logits(
    const int* __restrict__ src_arr, const int* __restrict__ dst_arr,
    const float* __restrict__ xl, const float* __restrict__ xr,
    const float* __restrict__ att, float* __restrict__ e, int nE, int n)
{
    const int wid  = (blockIdx.x * blockDim.x + threadIdx.x) >> 6;
    const int lane = threadIdx.x & 63;
    const int total = nE + n;
    if (wid >= total) return;
    int s, d;
    if (wid < nE) { s = src_arr[wid]; d = dst_arr[wid]; }
    else          { s = d = wid - nE; }
    const float* xls = xl + (size_t)s * C_DIM;
    const float* xrd = xr + (size_t)d * C_DIM;
    float acc = 0.f;
    #pragma unroll
    for (int c = lane; c < C_DIM; c += 64) {
        float z = xls[c] + xrd[c];
        float lr = z > 0.f ? z : NEG_SLOPE * z;
        acc = fmaf(lr, att[c], acc);
    }
    #pragma unroll
    for (int off = 32; off > 0; off >>= 1)
        acc += __shfl_down(acc, off);
    if (lane == 0) e[wid] = acc;
}

// ---------- K3: segment max over dst via atomicMax on mapped keys ----------
__global__ __launch_bounds__(256) void seg_max(
    const int* __restrict__ dst_arr, const float* __restrict__ e,
    unsigned* __restrict__ mkeys, int nE, int n)
{
    int j = blockIdx.x * blockDim.x + threadIdx.x;
    const int total = nE + n;
    if (j >= total) return;
    int d = (j < nE) ? dst_arr[j] : (j - nE);
    atomicMax(mkeys + d, f2key(e[j]));
}

// ---------- K5: ex = exp(e - m[dst]); denom[dst]+=ex; num[dst] += ex*xl[src] ----------
__global__ __launch_bounds__(256) void scatter_num(
    const int* __restrict__ src_arr, const int* __restrict__ dst_arr,
    const float* __restrict__ xl, const float* __restrict__ e,
    const unsigned* __restrict__ mkeys, float* __restrict__ denom,
    float* __restrict__ num, int nE, int n)
{
    const int wid  = (blockIdx.x * blockDim.x + threadIdx.x) >> 6;
    const int lane = threadIdx.x & 63;
    const int total = nE + n;
    if (wid >= total) return;
    int s, d;
    if (wid < nE) { s = src_arr[wid]; d = dst_arr[wid]; }
    else          { s = d = wid - nE; }
    const float m  = key2f(mkeys[d]);
    const float ex = __expf(e[wid] - m);        // <= 1 by construction
    if (lane == 0) atomicAdd(denom + d, ex);
    const float* xls = xl + (size_t)s * C_DIM;
    float* nd = num + (size_t)d * C_DIM;
    #pragma unroll
    for (int c = lane; c < C_DIM; c += 64)
        atomicAdd(nd + c, ex * xls[c]);
}

// ---------- K6: y = sigmoid(relu(num/denom + bias) . lw + lb) ----------
__global__ __launch_bounds__(256) void finalize(
    const float* __restrict__ num, const float* __restrict__ denom,
    const float* __restrict__ bias, const float* __restrict__ lw,
    const float* __restrict__ lb, float* __restrict__ y, int n)
{
    const int wid  = (blockIdx.x * blockDim.x + threadIdx.x) >> 6;
    const int lane = threadIdx.x & 63;
    if (wid >= n) return;
    const float invd = 1.f / denom[wid];        // denom >= 1 (self loop)
    const float* np_ = num + (size_t)wid * C_DIM;
    float acc = 0.f;
    #pragma unroll
    for (int c = lane; c < C_DIM; c += 64) {
        float h = fmaf(np_[c], invd, bias[c]);
        h = h > 0.f ? h : 0.f;
        acc = fmaf(h, lw[c], acc);
    }
    #pragma unroll
    for (int off = 32; off > 0; off >>= 1)
        acc += __shfl_down(acc, off);
    if (lane == 0) y[wid] = 1.f / (1.f + __expf(-(acc + lb[0])));
}

extern "C" void kernel_launch(void* const* d_in, const int* in_sizes, int n_in,
                              void* d_out, int out_size, void* d_ws, size_t ws_size,
                              hipStream_t stream)
{
    const float* x    = (const float*)d_in[0];
    const int*   ei   = (const int*)d_in[1];
    const float* Wl   = (const float*)d_in[2];
    const float* bl   = (const float*)d_in[3];
    const float* Wr   = (const float*)d_in[4];
    const float* br   = (const float*)d_in[5];
    const float* att  = (const float*)d_in[6];
    const float* bias = (const float*)d_in[7];
    const float* lw   = (const float*)d_in[8];
    const float* lb   = (const float*)d_in[9];
    float* y = (float*)d_out;

    const int n  = in_sizes[0] / F_IN;   // 50000
    const int nE = in_sizes[1] / 2;      // 800000
    const int total = nE + n;
    const int* src_arr = ei;             // edge_index[0]
    const int* dst_arr = ei + nE;        // edge_index[1]

    // workspace layout (floats): xl | xr(=num after K2) | e | mkeys | denom
    float*    xl    = (float*)d_ws;
    float*    xr    = xl + (size_t)n * C_DIM;
    float*    num   = xr;                               // alias: xr dead after K2
    float*    e     = xr + (size_t)n * C_DIM;
    unsigned* mkeys = (unsigned*)(e + total);
    float*    denom = (float*)(mkeys + n);

    // K1: dual GEMM
    dim3 g1((C_DIM + 63) / 64, (n + 31) / 32);
    gemm_xlxr<<<g1, 256, 0, stream>>>(x, Wl, bl, Wr, br, xl, xr, n);

    // K2: edge logits (4 waves / block)
    edge_logits<<<(total + 3) / 4, 256, 0, stream>>>(src_arr, dst_arr, xl, xr, att, e, nE, n);

    // init accumulators (after K2: num aliases xr)
    hipMemsetAsync(num,   0, (size_t)n * C_DIM * sizeof(float), stream);
    hipMemsetAsync(mkeys, 0, (size_t)n * sizeof(unsigned), stream);
    hipMemsetAsync(denom, 0, (size_t)n * sizeof(float), stream);

    // K3: segment max
    seg_max<<<(total + 255) / 256, 256, 0, stream>>>(dst_arr, e, mkeys, nE, n);

    // K5: fused exp + denom + numerator scatter
    scatter_num<<<(total + 3) / 4, 256, 0, stream>>>(src_arr, dst_arr, xl, e, mkeys, denom, num, nE, n);

    // K6: normalize + relu + linear head + sigmoid
    finalize<<<(n + 3) / 4, 256, 0, stream>>>(num, denom, bias, lw, lb, y, n);
}

// Round 2
// 630.593 us; speedup vs baseline: 2.5717x; 2.5717x over previous
//
#include <hip/hip_runtime.h>

#define F_IN 128
#define C_DIM 300
#define NC 5            // ceil(300/64) channels per lane
#define NEG_SLOPE 0.2f

// ---------- K1: xl = x@Wl + bl ; xr = x@Wr + br (fused) ----------
__global__ __launch_bounds__(256) void gemm_xlxr(
    const float* __restrict__ x, const float* __restrict__ Wl,
    const float* __restrict__ bl, const float* __restrict__ Wr,
    const float* __restrict__ br, float* __restrict__ xl,
    float* __restrict__ xr, int n)
{
    __shared__ __align__(16) float xs[32][F_IN];   // 16 KB
    const int row0 = blockIdx.y * 32;
    const int cb   = blockIdx.x * 64;
    const int t    = threadIdx.x;

    #pragma unroll
    for (int i = 0; i < 4; ++i) {
        int idx = (i * 256 + t) * 4;
        int r = idx >> 7;
        int k = idx & 127;
        int gr = row0 + r;
        if (gr >= n) gr = n - 1;
        *reinterpret_cast<float4*>(&xs[r][k]) =
            *reinterpret_cast<const float4*>(x + (size_t)gr * F_IN + k);
    }
    __syncthreads();

    const int tx = t & 63;
    const int ty = t >> 6;
    const int c  = cb + tx;
    if (c >= C_DIM) return;

    float accl[8], accr[8];
    #pragma unroll
    for (int i = 0; i < 8; ++i) { accl[i] = 0.f; accr[i] = 0.f; }

    const float* wlp = Wl + c;
    const float* wrp = Wr + c;
    #pragma unroll 4
    for (int k = 0; k < F_IN; ++k) {
        float wl = wlp[(size_t)k * C_DIM];
        float wr = wrp[(size_t)k * C_DIM];
        #pragma unroll
        for (int i = 0; i < 8; ++i) {
            float xv = xs[ty * 8 + i][k];
            accl[i] = fmaf(xv, wl, accl[i]);
            accr[i] = fmaf(xv, wr, accr[i]);
        }
    }
    const float blv = bl[c], brv = br[c];
    #pragma unroll
    for (int i = 0; i < 8; ++i) {
        int r = row0 + ty * 8 + i;
        if (r < n) {
            xl[(size_t)r * C_DIM + c] = accl[i] + blv;
            xr[(size_t)r * C_DIM + c] = accr[i] + brv;
        }
    }
}

// ---------- CSR build ----------
__global__ __launch_bounds__(256) void hist_kernel(
    const int* __restrict__ dst, unsigned* __restrict__ counts, int nE)
{
    int j = blockIdx.x * blockDim.x + threadIdx.x;
    if (j < nE) atomicAdd(counts + dst[j], 1u);
}

// single-block exclusive scan over n counts -> offs[n+1], and cursor copy
__global__ __launch_bounds__(1024) void scan_kernel(
    const unsigned* __restrict__ counts, unsigned* __restrict__ offs,
    unsigned* __restrict__ cursor, int n)
{
    __shared__ unsigned part[1024];
    const int t = threadIdx.x;
    const int chunk = (n + 1023) / 1024;
    const int lo = t * chunk;
    const int hi = min(lo + chunk, n);
    unsigned s = 0;
    for (int i = lo; i < hi; ++i) s += counts[i];
    part[t] = s;
    __syncthreads();
    for (int off = 1; off < 1024; off <<= 1) {
        unsigned v = (t >= off) ? part[t - off] : 0u;
        __syncthreads();
        if (t >= off) part[t] += v;
        __syncthreads();
    }
    unsigned base = (t == 0) ? 0u : part[t - 1];   // exclusive prefix of chunk
    for (int i = lo; i < hi; ++i) {
        unsigned c = counts[i];
        offs[i] = base;
        cursor[i] = base;
        base += c;
    }
    if (t == 1023) offs[n] = part[1023];           // total
}

__global__ __launch_bounds__(256) void scatter_csr(
    const int* __restrict__ src, const int* __restrict__ dst,
    unsigned* __restrict__ cursor, int* __restrict__ csr_src, int nE)
{
    int j = blockIdx.x * blockDim.x + threadIdx.x;
    if (j < nE) {
        unsigned p = atomicAdd(cursor + dst[j], 1u);
        csr_src[p] = src[j];
    }
}

// ---------- K2: fused per-node gather: logits + online softmax + aggregate + head ----------
// one wave per node
__global__ __launch_bounds__(256) void gat_gather(
    const int* __restrict__ csr_src, const unsigned* __restrict__ offs,
    const float* __restrict__ xl, const float* __restrict__ xr,
    const float* __restrict__ att, const float* __restrict__ bias,
    const float* __restrict__ lw, const float* __restrict__ lb,
    float* __restrict__ y, int n)
{
    const int wid  = (blockIdx.x * blockDim.x + threadIdx.x) >> 6;
    const int lane = threadIdx.x & 63;
    if (wid >= n) return;

    float att_r[NC], xr_r[NC], acc[NC];
    #pragma unroll
    for (int i = 0; i < NC; ++i) {
        int c = lane + i * 64;
        bool a = c < C_DIM;
        att_r[i] = a ? att[c] : 0.f;
        xr_r[i]  = a ? xr[(size_t)wid * C_DIM + c] : 0.f;
        acc[i]   = 0.f;
    }
    float m = -1e30f, den = 0.f;

    const unsigned start = offs[wid];
    const int deg = (int)(offs[wid + 1] - start);
    const int totalE = deg + 1;                     // + self loop (k==0)

    for (int base = 0; base < totalE; base += 64) {
        int k = base + lane;
        int sE = 0;
        if (k < totalE) sE = (k == 0) ? wid : csr_src[start + k - 1];
        const int cnt = min(64, totalE - base);
        for (int t = 0; t < cnt; ++t) {
            const int s = __shfl(sE, t);
            const float* xls = xl + (size_t)s * C_DIM;
            float xlv[NC];
            #pragma unroll
            for (int i = 0; i < NC; ++i) {
                int c = lane + i * 64;
                xlv[i] = (c < C_DIM) ? xls[c] : 0.f;
            }
            float ez = 0.f;
            #pragma unroll
            for (int i = 0; i < NC; ++i) {
                float z = xlv[i] + xr_r[i];
                float lr = z > 0.f ? z : NEG_SLOPE * z;
                ez = fmaf(lr, att_r[i], ez);
            }
            #pragma unroll
            for (int off = 32; off; off >>= 1) ez += __shfl_xor(ez, off);
            const float nm = fmaxf(m, ez);
            const float sc = __expf(m - nm);        // 1 if max unchanged
            const float w  = __expf(ez - nm);
            den = den * sc + w;
            #pragma unroll
            for (int i = 0; i < NC; ++i) acc[i] = fmaf(acc[i], sc, w * xlv[i]);
            m = nm;
        }
    }

    const float invd = 1.f / den;
    float dot = 0.f;
    #pragma unroll
    for (int i = 0; i < NC; ++i) {
        int c = lane + i * 64;
        float b = (c < C_DIM) ? bias[c] : 0.f;
        float l = (c < C_DIM) ? lw[c] : 0.f;
        float h = fmaf(acc[i], invd, b);
        h = h > 0.f ? h : 0.f;
        dot = fmaf(h, l, dot);
    }
    #pragma unroll
    for (int off = 32; off; off >>= 1) dot += __shfl_xor(dot, off);
    if (lane == 0) y[wid] = 1.f / (1.f + __expf(-(dot + lb[0])));
}

extern "C" void kernel_launch(void* const* d_in, const int* in_sizes, int n_in,
                              void* d_out, int out_size, void* d_ws, size_t ws_size,
                              hipStream_t stream)
{
    const float* x    = (const float*)d_in[0];
    const int*   ei   = (const int*)d_in[1];
    const float* Wl   = (const float*)d_in[2];
    const float* bl   = (const float*)d_in[3];
    const float* Wr   = (const float*)d_in[4];
    const float* br   = (const float*)d_in[5];
    const float* att  = (const float*)d_in[6];
    const float* bias = (const float*)d_in[7];
    const float* lw   = (const float*)d_in[8];
    const float* lb   = (const float*)d_in[9];
    float* y = (float*)d_out;

    const int n  = in_sizes[0] / F_IN;   // 50000
    const int nE = in_sizes[1] / 2;      // 800000
    const int* src_arr = ei;             // edge_index[0]
    const int* dst_arr = ei + nE;        // edge_index[1]

    // workspace layout: xl | xr | counts | offs(n+1) | cursor | csr_src
    float*    xl      = (float*)d_ws;
    float*    xr      = xl + (size_t)n * C_DIM;
    unsigned* counts  = (unsigned*)(xr + (size_t)n * C_DIM);
    unsigned* offs    = counts + n;
    unsigned* cursor  = offs + (n + 1);
    int*      csr_src = (int*)(cursor + n);

    // K1: dual GEMM
    dim3 g1((C_DIM + 63) / 64, (n + 31) / 32);
    gemm_xlxr<<<g1, 256, 0, stream>>>(x, Wl, bl, Wr, br, xl, xr, n);

    // CSR build (independent of GEMM)
    hipMemsetAsync(counts, 0, (size_t)n * sizeof(unsigned), stream);
    hist_kernel<<<(nE + 255) / 256, 256, 0, stream>>>(dst_arr, counts, nE);
    scan_kernel<<<1, 1024, 0, stream>>>(counts, offs, cursor, n);
    scatter_csr<<<(nE + 255) / 256, 256, 0, stream>>>(src_arr, dst_arr, cursor, csr_src, nE);

    // K2: fused gather + online softmax + aggregate + head
    gat_gather<<<(n + 3) / 4, 256, 0, stream>>>(csr_src, offs, xl, xr, att, bias, lw, lb, y, n);
}

// Round 3
// 580.779 us; speedup vs baseline: 2.7923x; 1.0858x over previous
//
#include <hip/hip_runtime.h>
#include <hip/hip_fp16.h>

#define F_IN 128
#define C_DIM 300
#define NEG_SLOPE 0.2f

__device__ inline float2 up2(unsigned u) {
    __half2 h;
    *reinterpret_cast<unsigned*>(&h) = u;
    return __half22float2(h);
}

// ---------- K1: xl = x@Wl + bl ; xr = x@Wr + br (fused), fp16 outputs ----------
// grid: (ceil(C/64), ceil(n/32)), block 256 = (64 cols) x (4 row-groups of 8)
__global__ __launch_bounds__(256) void gemm_xlxr(
    const float* __restrict__ x, const float* __restrict__ Wl,
    const float* __restrict__ bl, const float* __restrict__ Wr,
    const float* __restrict__ br, __half* __restrict__ xlh,
    __half* __restrict__ xrh, int n)
{
    __shared__ __align__(16) float xs[32][F_IN];   // 16 KB
    const int row0 = blockIdx.y * 32;
    const int cb   = blockIdx.x * 64;
    const int t    = threadIdx.x;

    #pragma unroll
    for (int i = 0; i < 4; ++i) {
        int idx = (i * 256 + t) * 4;
        int r = idx >> 7;
        int k = idx & 127;
        int gr = row0 + r;
        if (gr >= n) gr = n - 1;
        *reinterpret_cast<float4*>(&xs[r][k]) =
            *reinterpret_cast<const float4*>(x + (size_t)gr * F_IN + k);
    }
    __syncthreads();

    const int tx = t & 63;
    const int ty = t >> 6;
    const int c  = cb + tx;
    if (c >= C_DIM) return;

    float accl[8], accr[8];
    #pragma unroll
    for (int i = 0; i < 8; ++i) { accl[i] = 0.f; accr[i] = 0.f; }

    const float* wlp = Wl + c;
    const float* wrp = Wr + c;
    #pragma unroll 4
    for (int k = 0; k < F_IN; ++k) {
        float wl = wlp[(size_t)k * C_DIM];
        float wr = wrp[(size_t)k * C_DIM];
        #pragma unroll
        for (int i = 0; i < 8; ++i) {
            float xv = xs[ty * 8 + i][k];
            accl[i] = fmaf(xv, wl, accl[i]);
            accr[i] = fmaf(xv, wr, accr[i]);
        }
    }
    const float blv = bl[c], brv = br[c];
    #pragma unroll
    for (int i = 0; i < 8; ++i) {
        int r = row0 + ty * 8 + i;
        if (r < n) {
            xlh[(size_t)r * C_DIM + c] = __float2half(accl[i] + blv);
            xrh[(size_t)r * C_DIM + c] = __float2half(accr[i] + brv);
        }
    }
}

// ---------- CSR build ----------
__global__ __launch_bounds__(256) void hist_kernel(
    const int* __restrict__ dst, unsigned* __restrict__ counts, int nE)
{
    int j = blockIdx.x * blockDim.x + threadIdx.x;
    if (j < nE) atomicAdd(counts + dst[j], 1u);
}

__global__ __launch_bounds__(1024) void scan_kernel(
    const unsigned* __restrict__ counts, unsigned* __restrict__ offs,
    unsigned* __restrict__ cursor, int n)
{
    __shared__ unsigned part[1024];
    const int t = threadIdx.x;
    const int chunk = (n + 1023) / 1024;
    const int lo = t * chunk;
    const int hi = min(lo + chunk, n);
    unsigned s = 0;
    for (int i = lo; i < hi; ++i) s += counts[i];
    part[t] = s;
    __syncthreads();
    for (int off = 1; off < 1024; off <<= 1) {
        unsigned v = (t >= off) ? part[t - off] : 0u;
        __syncthreads();
        if (t >= off) part[t] += v;
        __syncthreads();
    }
    unsigned base = (t == 0) ? 0u : part[t - 1];
    for (int i = lo; i < hi; ++i) {
        unsigned c = counts[i];
        offs[i] = base;
        cursor[i] = base;
        base += c;
    }
    if (t == 1023) offs[n] = part[1023];
}

__global__ __launch_bounds__(256) void scatter_csr(
    const int* __restrict__ src, const int* __restrict__ dst,
    unsigned* __restrict__ cursor, int* __restrict__ csr_src, int nE)
{
    int j = blockIdx.x * blockDim.x + threadIdx.x;
    if (j < nE) {
        unsigned p = atomicAdd(cursor + dst[j], 1u);
        csr_src[p] = src[j];
    }
}

// ---------- K2: fused per-node gather: logits + online softmax + aggregate + head ----------
// one wave per node; lane owns channels c = 128k + 2*lane + j, k in [0,3), j in [0,2)
__global__ __launch_bounds__(256) void gat_gather(
    const int* __restrict__ csr_src, const unsigned* __restrict__ offs,
    const __half* __restrict__ xlh, const __half* __restrict__ xrh,
    const float* __restrict__ att, const float* __restrict__ bias,
    const float* __restrict__ lw, const float* __restrict__ lb,
    float* __restrict__ y, int n)
{
    const int wid  = (blockIdx.x * blockDim.x + threadIdx.x) >> 6;
    const int lane = threadIdx.x & 63;
    if (wid >= n) return;

    const int l2 = 2 * lane;
    const bool has2 = (lane < 22);          // k=2 slot valid: 256+2*lane < 300

    // xr row (fp16 -> fp32)
    const __half* xrrow = xrh + (size_t)wid * C_DIM;
    float2 r0 = up2(*(const unsigned*)((const unsigned short*)xrrow + l2));
    float2 r1 = up2(*(const unsigned*)((const unsigned short*)xrrow + 128 + l2));
    float2 r2 = has2 ? up2(*(const unsigned*)((const unsigned short*)xrrow + 256 + l2))
                     : make_float2(0.f, 0.f);
    float xr_r[6] = {r0.x, r0.y, r1.x, r1.y, r2.x, r2.y};

    float att_r[6], acc[6];
    #pragma unroll
    for (int k = 0; k < 3; ++k) {
        #pragma unroll
        for (int j = 0; j < 2; ++j) {
            int c = 128 * k + l2 + j;
            att_r[2 * k + j] = (c < C_DIM) ? att[c] : 0.f;
            acc[2 * k + j] = 0.f;
        }
    }

    float m = -1e30f, den = 0.f;
    const unsigned start = offs[wid];
    const int deg = (int)(offs[wid + 1] - start);
    const int totalE = deg + 1;             // + self loop (k==0)

    for (int base = 0; base < totalE; base += 64) {
        int ke = base + lane;
        int sE = 0;
        if (ke < totalE) sE = (ke == 0) ? wid : csr_src[start + ke - 1];
        const int cnt = min(64, totalE - base);

        // prefetch edge 0 of this block
        int s0 = __shfl(sE, 0);
        const unsigned short* rp = (const unsigned short*)(xlh + (size_t)s0 * C_DIM);
        unsigned pa0 = *(const unsigned*)(rp + l2);
        unsigned pa1 = *(const unsigned*)(rp + 128 + l2);
        unsigned pa2 = has2 ? *(const unsigned*)(rp + 256 + l2) : 0u;

        for (int t = 0; t < cnt; ++t) {
            unsigned pb0 = 0, pb1 = 0, pb2 = 0;
            if (t + 1 < cnt) {
                int s1 = __shfl(sE, t + 1);
                const unsigned short* rq = (const unsigned short*)(xlh + (size_t)s1 * C_DIM);
                pb0 = *(const unsigned*)(rq + l2);
                pb1 = *(const unsigned*)(rq + 128 + l2);
                pb2 = has2 ? *(const unsigned*)(rq + 256 + l2) : 0u;
            }
            float2 f0 = up2(pa0), f1 = up2(pa1), f2 = up2(pa2);
            float xlv[6] = {f0.x, f0.y, f1.x, f1.y, f2.x, f2.y};

            float ez = 0.f;
            #pragma unroll
            for (int i = 0; i < 6; ++i) {
                float z = xlv[i] + xr_r[i];
                float lr = z > 0.f ? z : NEG_SLOPE * z;
                ez = fmaf(lr, att_r[i], ez);
            }
            #pragma unroll
            for (int off = 32; off; off >>= 1) ez += __shfl_xor(ez, off);

            const float nm = fmaxf(m, ez);
            const float sc = __expf(m - nm);
            const float w  = __expf(ez - nm);
            den = den * sc + w;
            #pragma unroll
            for (int i = 0; i < 6; ++i) acc[i] = fmaf(acc[i], sc, w * xlv[i]);
            m = nm;

            pa0 = pb0; pa1 = pb1; pa2 = pb2;
        }
    }

    const float invd = 1.f / den;
    float dot = 0.f;
    #pragma unroll
    for (int k = 0; k < 3; ++k) {
        #pragma unroll
        for (int j = 0; j < 2; ++j) {
            int c = 128 * k + l2 + j;
            float b = (c < C_DIM) ? bias[c] : 0.f;
            float l = (c < C_DIM) ? lw[c] : 0.f;
            float h = fmaf(acc[2 * k + j], invd, b);
            h = h > 0.f ? h : 0.f;
            dot = fmaf(h, l, dot);
        }
    }
    #pragma unroll
    for (int off = 32; off; off >>= 1) dot += __shfl_xor(dot, off);
    if (lane == 0) y[wid] = 1.f / (1.f + __expf(-(dot + lb[0])));
}

extern "C" void kernel_launch(void* const* d_in, const int* in_sizes, int n_in,
                              void* d_out, int out_size, void* d_ws, size_t ws_size,
                              hipStream_t stream)
{
    const float* x    = (const float*)d_in[0];
    const int*   ei   = (const int*)d_in[1];
    const float* Wl   = (const float*)d_in[2];
    const float* bl   = (const float*)d_in[3];
    const float* Wr   = (const float*)d_in[4];
    const float* br   = (const float*)d_in[5];
    const float* att  = (const float*)d_in[6];
    const float* bias = (const float*)d_in[7];
    const float* lw   = (const float*)d_in[8];
    const float* lb   = (const float*)d_in[9];
    float* y = (float*)d_out;

    const int n  = in_sizes[0] / F_IN;   // 50000
    const int nE = in_sizes[1] / 2;      // 800000
    const int* src_arr = ei;             // edge_index[0]
    const int* dst_arr = ei + nE;        // edge_index[1]

    // workspace layout: xlh | xrh (fp16) | counts | offs(n+1) | cursor | csr_src
    __half*   xlh     = (__half*)d_ws;
    __half*   xrh     = xlh + (size_t)n * C_DIM;
    unsigned* counts  = (unsigned*)(xrh + (size_t)n * C_DIM);
    unsigned* offs    = counts + n;
    unsigned* cursor  = offs + (n + 1);
    int*      csr_src = (int*)(cursor + n);

    // K1: dual GEMM -> fp16 tables
    dim3 g1((C_DIM + 63) / 64, (n + 31) / 32);
    gemm_xlxr<<<g1, 256, 0, stream>>>(x, Wl, bl, Wr, br, xlh, xrh, n);

    // CSR build
    hipMemsetAsync(counts, 0, (size_t)n * sizeof(unsigned), stream);
    hist_kernel<<<(nE + 255) / 256, 256, 0, stream>>>(dst_arr, counts, nE);
    scan_kernel<<<1, 1024, 0, stream>>>(counts, offs, cursor, n);
    scatter_csr<<<(nE + 255) / 256, 256, 0, stream>>>(src_arr, dst_arr, cursor, csr_src, nE);

    // K2: fused gather + online softmax + aggregate + head
    gat_gather<<<(n + 3) / 4, 256, 0, stream>>>(csr_src, offs, xlh, xrh, att, bias, lw, lb, y, n);
}

// Round 4
// 465.822 us; speedup vs baseline: 3.4814x; 1.2468x over previous
//
#include <hip/hip_runtime.h>
#include <hip/hip_fp16.h>

#define F_IN 128
#define C_DIM 300
#define NEG_SLOPE 0.2f
#define NPAD 608          // 2*304: Wl cols [0,300), pad, Wr cols [304,604), pad
#define NCT  40           // padded col-tile count for Bp (covers bx*64+63 < 640)

typedef _Float16 half8 __attribute__((ext_vector_type(8)));
typedef _Float16 half4 __attribute__((ext_vector_type(4)));
typedef float    f32x4 __attribute__((ext_vector_type(4)));

__device__ inline float2 up2(unsigned u) {
    __half2 h;
    *reinterpret_cast<unsigned*>(&h) = u;
    return __half22float2(h);
}

// ---------- K0: build fragment-ready f16 weight layout ----------
// Bp[((ct*4+ks)*64 + lane)*8 + j] = Wcat[k][n], n = ct*16 + (lane&15),
// k = ks*32 + (lane>>4)*8 + j ; Wcat = [Wl | 0 | Wr | 0] (NPAD cols)
__global__ __launch_bounds__(256) void convert_w(
    const float* __restrict__ Wl, const float* __restrict__ Wr,
    _Float16* __restrict__ Bp)
{
    int idx = blockIdx.x * 256 + threadIdx.x;        // 0 .. NCT*4*64*8-1
    if (idx >= NCT * 4 * 64 * 8) return;
    int j    = idx & 7;
    int lane = (idx >> 3) & 63;
    int kc   = idx >> 9;
    int ks   = kc & 3;
    int ct   = kc >> 2;
    int nn   = ct * 16 + (lane & 15);
    int k    = ks * 32 + (lane >> 4) * 8 + j;
    float v = 0.f;
    if (nn < 300)                 v = Wl[(size_t)k * C_DIM + nn];
    else if (nn >= 304 && nn < 604) v = Wr[(size_t)k * C_DIM + (nn - 304)];
    Bp[idx] = (_Float16)v;
}

// ---------- K1: dual GEMM via f16 MFMA; writes f16 tables ----------
// grid: (10 col-blocks of 64, ceil(n/64) row-blocks), block 256 = 4 waves
// wave w computes rows [rb0+16w, rb0+16w+16) x cols [nb0, nb0+64)
__global__ __launch_bounds__(256) void gemm_xlxr(
    const float* __restrict__ x, const _Float16* __restrict__ Bp,
    const float* __restrict__ bl, const float* __restrict__ br,
    _Float16* __restrict__ xlh, _Float16* __restrict__ xrh, int n)
{
    __shared__ __align__(16) _Float16 xs[64][136];   // 17.4 KB, row = 272 B
    const int rb0 = blockIdx.y * 64;
    const int nb0 = blockIdx.x * 64;
    const int t   = threadIdx.x;

    // stage 64 rows x 128 k of x, fp32 -> f16
    #pragma unroll
    for (int i = 0; i < 8; ++i) {
        int flat = (i * 256 + t) * 4;                // 0..8191 step 4
        int r = flat >> 7;
        int k = flat & 127;
        int gr = rb0 + r;
        if (gr >= n) gr = n - 1;
        float4 v = *reinterpret_cast<const float4*>(x + (size_t)gr * F_IN + k);
        half4 h = { (_Float16)v.x, (_Float16)v.y, (_Float16)v.z, (_Float16)v.w };
        *reinterpret_cast<half4*>(&xs[r][k]) = h;
    }
    __syncthreads();

    const int w    = t >> 6;
    const int lane = t & 63;
    const int m    = lane & 15;
    const int quad = lane >> 4;

    f32x4 acc[4] = {{0,0,0,0},{0,0,0,0},{0,0,0,0},{0,0,0,0}};

    #pragma unroll
    for (int ks = 0; ks < 4; ++ks) {
        half8 a = *reinterpret_cast<const half8*>(&xs[w * 16 + m][ks * 32 + quad * 8]);
        #pragma unroll
        for (int cf = 0; cf < 4; ++cf) {
            int ct = (nb0 >> 4) + cf;
            half8 b = *reinterpret_cast<const half8*>(
                Bp + (((size_t)(ct * 4 + ks) * 64 + lane) << 3));
            acc[cf] = __builtin_amdgcn_mfma_f32_16x16x32_f16(a, b, acc[cf], 0, 0, 0);
        }
    }

    // epilogue: + bias, f16 store into xlh / xrh
    #pragma unroll
    for (int cf = 0; cf < 4; ++cf) {
        int col = nb0 + cf * 16 + m;
        float bv = 0.f;
        int isL = (col < 300);
        int isR = (col >= 304 && col < 604);
        if (isL) bv = bl[col];
        else if (isR) bv = br[col - 304];
        #pragma unroll
        for (int reg = 0; reg < 4; ++reg) {
            int row = rb0 + w * 16 + quad * 4 + reg;
            if (row < n) {
                _Float16 hv = (_Float16)(acc[cf][reg] + bv);
                if (isL)      xlh[(size_t)row * C_DIM + col] = hv;
                else if (isR) xrh[(size_t)row * C_DIM + (col - 304)] = hv;
            }
        }
    }
}

// ---------- CSR build ----------
__global__ __launch_bounds__(256) void hist_kernel(
    const int* __restrict__ dst, unsigned* __restrict__ counts, int nE)
{
    int j = blockIdx.x * blockDim.x + threadIdx.x;
    if (j < nE) atomicAdd(counts + dst[j], 1u);
}

__global__ __launch_bounds__(1024) void scan_kernel(
    const unsigned* __restrict__ counts, unsigned* __restrict__ offs,
    unsigned* __restrict__ cursor, int n)
{
    __shared__ unsigned part[1024];
    const int t = threadIdx.x;
    const int chunk = (n + 1023) / 1024;
    const int lo = t * chunk;
    const int hi = min(lo + chunk, n);
    unsigned s = 0;
    for (int i = lo; i < hi; ++i) s += counts[i];
    part[t] = s;
    __syncthreads();
    for (int off = 1; off < 1024; off <<= 1) {
        unsigned v = (t >= off) ? part[t - off] : 0u;
        __syncthreads();
        if (t >= off) part[t] += v;
        __syncthreads();
    }
    unsigned base = (t == 0) ? 0u : part[t - 1];
    for (int i = lo; i < hi; ++i) {
        unsigned c = counts[i];
        offs[i] = base;
        cursor[i] = base;
        base += c;
    }
    if (t == 1023) offs[n] = part[1023];
}

__global__ __launch_bounds__(256) void scatter_csr(
    const int* __restrict__ src, const int* __restrict__ dst,
    unsigned* __restrict__ cursor, int* __restrict__ csr_src, int nE)
{
    int j = blockIdx.x * blockDim.x + threadIdx.x;
    if (j < nE) {
        unsigned p = atomicAdd(cursor + dst[j], 1u);
        csr_src[p] = src[j];
    }
}

// ---------- K2: fused per-node gather: logits + online softmax + aggregate + head ----------
__global__ __launch_bounds__(256) void gat_gather(
    const int* __restrict__ csr_src, const unsigned* __restrict__ offs,
    const _Float16* __restrict__ xlh, const _Float16* __restrict__ xrh,
    const float* __restrict__ att, const float* __restrict__ bias,
    const float* __restrict__ lw, const float* __restrict__ lb,
    float* __restrict__ y, int n)
{
    const int wid  = (blockIdx.x * blockDim.x + threadIdx.x) >> 6;
    const int lane = threadIdx.x & 63;
    if (wid >= n) return;

    const int l2 = 2 * lane;
    const bool has2 = (lane < 22);

    const unsigned short* xrrow = (const unsigned short*)(xrh + (size_t)wid * C_DIM);
    float2 r0 = up2(*(const unsigned*)(xrrow + l2));
    float2 r1 = up2(*(const unsigned*)(xrrow + 128 + l2));
    float2 r2 = has2 ? up2(*(const unsigned*)(xrrow + 256 + l2)) : make_float2(0.f, 0.f);
    float xr_r[6] = {r0.x, r0.y, r1.x, r1.y, r2.x, r2.y};

    float att_r[6], acc[6];
    #pragma unroll
    for (int k = 0; k < 3; ++k)
        #pragma unroll
        for (int j = 0; j < 2; ++j) {
            int c = 128 * k + l2 + j;
            att_r[2 * k + j] = (c < C_DIM) ? att[c] : 0.f;
            acc[2 * k + j] = 0.f;
        }

    float m = -1e30f, den = 0.f;
    const unsigned start = offs[wid];
    const int deg = (int)(offs[wid + 1] - start);
    const int totalE = deg + 1;

    for (int base = 0; base < totalE; base += 64) {
        int ke = base + lane;
        int sE = 0;
        if (ke < totalE) sE = (ke == 0) ? wid : csr_src[start + ke - 1];
        const int cnt = min(64, totalE - base);

        int s0 = __shfl(sE, 0);
        const unsigned short* rp = (const unsigned short*)(xlh + (size_t)s0 * C_DIM);
        unsigned pa0 = *(const unsigned*)(rp + l2);
        unsigned pa1 = *(const unsigned*)(rp + 128 + l2);
        unsigned pa2 = has2 ? *(const unsigned*)(rp + 256 + l2) : 0u;

        for (int t = 0; t < cnt; ++t) {
            unsigned pb0 = 0, pb1 = 0, pb2 = 0;
            if (t + 1 < cnt) {
                int s1 = __shfl(sE, t + 1);
                const unsigned short* rq = (const unsigned short*)(xlh + (size_t)s1 * C_DIM);
                pb0 = *(const unsigned*)(rq + l2);
                pb1 = *(const unsigned*)(rq + 128 + l2);
                pb2 = has2 ? *(const unsigned*)(rq + 256 + l2) : 0u;
            }
            float2 f0 = up2(pa0), f1 = up2(pa1), f2 = up2(pa2);
            float xlv[6] = {f0.x, f0.y, f1.x, f1.y, f2.x, f2.y};

            float ez = 0.f;
            #pragma unroll
            for (int i = 0; i < 6; ++i) {
                float z = xlv[i] + xr_r[i];
                float lr = z > 0.f ? z : NEG_SLOPE * z;
                ez = fmaf(lr, att_r[i], ez);
            }
            #pragma unroll
            for (int off = 32; off; off >>= 1) ez += __shfl_xor(ez, off);

            const float nm = fmaxf(m, ez);
            const float sc = __expf(m - nm);
            const float wgt = __expf(ez - nm);
            den = den * sc + wgt;
            #pragma unroll
            for (int i = 0; i < 6; ++i) acc[i] = fmaf(acc[i], sc, wgt * xlv[i]);
            m = nm;

            pa0 = pb0; pa1 = pb1; pa2 = pb2;
        }
    }

    const float invd = 1.f / den;
    float dot = 0.f;
    #pragma unroll
    for (int k = 0; k < 3; ++k)
        #pragma unroll
        for (int j = 0; j < 2; ++j) {
            int c = 128 * k + l2 + j;
            float b = (c < C_DIM) ? bias[c] : 0.f;
            float l = (c < C_DIM) ? lw[c] : 0.f;
            float h = fmaf(acc[2 * k + j], invd, b);
            h = h > 0.f ? h : 0.f;
            dot = fmaf(h, l, dot);
        }
    #pragma unroll
    for (int off = 32; off; off >>= 1) dot += __shfl_xor(dot, off);
    if (lane == 0) y[wid] = 1.f / (1.f + __expf(-(dot + lb[0])));
}

extern "C" void kernel_launch(void* const* d_in, const int* in_sizes, int n_in,
                              void* d_out, int out_size, void* d_ws, size_t ws_size,
                              hipStream_t stream)
{
    const float* x    = (const float*)d_in[0];
    const int*   ei   = (const int*)d_in[1];
    const float* Wl   = (const float*)d_in[2];
    const float* bl   = (const float*)d_in[3];
    const float* Wr   = (const float*)d_in[4];
    const float* br   = (const float*)d_in[5];
    const float* att  = (const float*)d_in[6];
    const float* bias = (const float*)d_in[7];
    const float* lw   = (const float*)d_in[8];
    const float* lb   = (const float*)d_in[9];
    float* y = (float*)d_out;

    const int n  = in_sizes[0] / F_IN;   // 50000
    const int nE = in_sizes[1] / 2;      // 800000
    const int* src_arr = ei;
    const int* dst_arr = ei + nE;

    // ws: xlh | xrh | Bp | counts | offs(n+1) | cursor | csr_src
    _Float16* xlh     = (_Float16*)d_ws;
    _Float16* xrh     = xlh + (size_t)n * C_DIM;
    _Float16* Bp      = xrh + (size_t)n * C_DIM;
    unsigned* counts  = (unsigned*)(Bp + NCT * 4 * 64 * 8);
    unsigned* offs    = counts + n;
    unsigned* cursor  = offs + (n + 1);
    int*      csr_src = (int*)(cursor + n);

    // weight repack + CSR build (independent)
    convert_w<<<(NCT * 4 * 64 * 8 + 255) / 256, 256, 0, stream>>>(Wl, Wr, Bp);
    hipMemsetAsync(counts, 0, (size_t)n * sizeof(unsigned), stream);
    hist_kernel<<<(nE + 255) / 256, 256, 0, stream>>>(dst_arr, counts, nE);
    scan_kernel<<<1, 1024, 0, stream>>>(counts, offs, cursor, n);
    scatter_csr<<<(nE + 255) / 256, 256, 0, stream>>>(src_arr, dst_arr, cursor, csr_src, nE);

    // MFMA dual GEMM -> f16 tables
    dim3 g1(NPAD / 64 + 1, (n + 63) / 64);           // 10 x 782
    gemm_xlxr<<<g1, 256, 0, stream>>>(x, Bp, bl, br, xlh, xrh, n);

    // fused gather + online softmax + aggregate + head
    gat_gather<<<(n + 3) / 4, 256, 0, stream>>>(csr_src, offs, xlh, xrh, att, bias, lw, lb, y, n);
}

// Round 5
// 438.715 us; speedup vs baseline: 3.6965x; 1.0618x over previous
//
#include <hip/hip_runtime.h>
#include <hip/hip_fp16.h>

#define F_IN 128
#define C_DIM 300
#define NEG_SLOPE 0.2f
#define NPAD 608          // 2*304: Wl cols [0,300), pad, Wr cols [304,604), pad
#define NCT  40           // padded col-tile count for Bp
#define CH   16           // edges per chunk in gat_gather

typedef _Float16 half8 __attribute__((ext_vector_type(8)));
typedef _Float16 half4 __attribute__((ext_vector_type(4)));
typedef _Float16 h2    __attribute__((ext_vector_type(2)));
typedef float    f32x4 __attribute__((ext_vector_type(4)));

__device__ inline float2 up2(unsigned u) {
    __half2 h;
    *reinterpret_cast<unsigned*>(&h) = u;
    return __half22float2(h);
}
__device__ inline h2 as_h2(unsigned u) { union { unsigned u; h2 h; } c; c.u = u; return c.h; }
__device__ inline unsigned as_u(h2 h)  { union { unsigned u; h2 h; } c; c.h = h; return c.u; }

#if __has_builtin(__builtin_amdgcn_fdot2)
__device__ inline float fdot2w(h2 a, h2 b, float c) {
    return __builtin_amdgcn_fdot2(a, b, c, false);
}
#else
__device__ inline float fdot2w(h2 a, h2 b, float c) {
    return fmaf((float)a.y, (float)b.y, fmaf((float)a.x, (float)b.x, c));
}
#endif

// ---------- K0: build fragment-ready f16 weight layout ----------
__global__ __launch_bounds__(256) void convert_w(
    const float* __restrict__ Wl, const float* __restrict__ Wr,
    _Float16* __restrict__ Bp)
{
    int idx = blockIdx.x * 256 + threadIdx.x;
    if (idx >= NCT * 4 * 64 * 8) return;
    int j    = idx & 7;
    int lane = (idx >> 3) & 63;
    int kc   = idx >> 9;
    int ks   = kc & 3;
    int ct   = kc >> 2;
    int nn   = ct * 16 + (lane & 15);
    int k    = ks * 32 + (lane >> 4) * 8 + j;
    float v = 0.f;
    if (nn < 300)                   v = Wl[(size_t)k * C_DIM + nn];
    else if (nn >= 304 && nn < 604) v = Wr[(size_t)k * C_DIM + (nn - 304)];
    Bp[idx] = (_Float16)v;
}

// ---------- K1: dual GEMM via f16 MFMA; writes f16 tables ----------
__global__ __launch_bounds__(256) void gemm_xlxr(
    const float* __restrict__ x, const _Float16* __restrict__ Bp,
    const float* __restrict__ bl, const float* __restrict__ br,
    _Float16* __restrict__ xlh, _Float16* __restrict__ xrh, int n)
{
    __shared__ __align__(16) _Float16 xs[64][136];
    const int rb0 = blockIdx.y * 64;
    const int nb0 = blockIdx.x * 64;
    const int t   = threadIdx.x;

    #pragma unroll
    for (int i = 0; i < 8; ++i) {
        int flat = (i * 256 + t) * 4;
        int r = flat >> 7;
        int k = flat & 127;
        int gr = rb0 + r;
        if (gr >= n) gr = n - 1;
        float4 v = *reinterpret_cast<const float4*>(x + (size_t)gr * F_IN + k);
        half4 h = { (_Float16)v.x, (_Float16)v.y, (_Float16)v.z, (_Float16)v.w };
        *reinterpret_cast<half4*>(&xs[r][k]) = h;
    }
    __syncthreads();

    const int w    = t >> 6;
    const int lane = t & 63;
    const int m    = lane & 15;
    const int quad = lane >> 4;

    f32x4 acc[4] = {{0,0,0,0},{0,0,0,0},{0,0,0,0},{0,0,0,0}};

    #pragma unroll
    for (int ks = 0; ks < 4; ++ks) {
        half8 a = *reinterpret_cast<const half8*>(&xs[w * 16 + m][ks * 32 + quad * 8]);
        #pragma unroll
        for (int cf = 0; cf < 4; ++cf) {
            int ct = (nb0 >> 4) + cf;
            half8 b = *reinterpret_cast<const half8*>(
                Bp + (((size_t)(ct * 4 + ks) * 64 + lane) << 3));
            acc[cf] = __builtin_amdgcn_mfma_f32_16x16x32_f16(a, b, acc[cf], 0, 0, 0);
        }
    }

    #pragma unroll
    for (int cf = 0; cf < 4; ++cf) {
        int col = nb0 + cf * 16 + m;
        float bv = 0.f;
        int isL = (col < 300);
        int isR = (col >= 304 && col < 604);
        if (isL) bv = bl[col];
        else if (isR) bv = br[col - 304];
        #pragma unroll
        for (int reg = 0; reg < 4; ++reg) {
            int row = rb0 + w * 16 + quad * 4 + reg;
            if (row < n) {
                _Float16 hv = (_Float16)(acc[cf][reg] + bv);
                if (isL)      xlh[(size_t)row * C_DIM + col] = hv;
                else if (isR) xrh[(size_t)row * C_DIM + (col - 304)] = hv;
            }
        }
    }
}

// ---------- CSR build ----------
__global__ __launch_bounds__(256) void hist_kernel(
    const int* __restrict__ dst, unsigned* __restrict__ counts, int nE)
{
    int j = blockIdx.x * blockDim.x + threadIdx.x;
    if (j < nE) atomicAdd(counts + dst[j], 1u);
}

__global__ __launch_bounds__(1024) void scan_kernel(
    const unsigned* __restrict__ counts, unsigned* __restrict__ offs,
    unsigned* __restrict__ cursor, int n)
{
    __shared__ unsigned part[1024];
    const int t = threadIdx.x;
    const int chunk = (n + 1023) / 1024;
    const int lo = t * chunk;
    const int hi = min(lo + chunk, n);
    unsigned s = 0;
    for (int i = lo; i < hi; ++i) s += counts[i];
    part[t] = s;
    __syncthreads();
    for (int off = 1; off < 1024; off <<= 1) {
        unsigned v = (t >= off) ? part[t - off] : 0u;
        __syncthreads();
        if (t >= off) part[t] += v;
        __syncthreads();
    }
    unsigned base = (t == 0) ? 0u : part[t - 1];
    for (int i = lo; i < hi; ++i) {
        unsigned c = counts[i];
        offs[i] = base;
        cursor[i] = base;
        base += c;
    }
    if (t == 1023) offs[n] = part[1023];
}

__global__ __launch_bounds__(256) void scatter_csr(
    const int* __restrict__ src, const int* __restrict__ dst,
    unsigned* __restrict__ cursor, int* __restrict__ csr_src, int nE)
{
    int j = blockIdx.x * blockDim.x + threadIdx.x;
    if (j < nE) {
        unsigned p = atomicAdd(cursor + dst[j], 1u);
        csr_src[p] = src[j];
    }
}

// ---------- K2: fused per-node gather, chunked softmax (16 edges/iter) ----------
// one wave per node; lane owns channels c = 128k + 2*lane + j
// logits: att . leaky(z) == dot(z, 0.6*att) + dot(|z|, 0.4*att)  (slope 0.2)
// fixed-base softmax (logits are O(1); clamp at 60 guards overflow; per-node
// max subtraction is mathematically redundant for the ratio)
__global__ __launch_bounds__(256) void gat_gather(
    const int* __restrict__ csr_src, const unsigned* __restrict__ offs,
    const _Float16* __restrict__ xlh, const _Float16* __restrict__ xrh,
    const float* __restrict__ att, const float* __restrict__ bias,
    const float* __restrict__ lw, const float* __restrict__ lb,
    float* __restrict__ y, int n)
{
    __shared__ __align__(16) float lds[4 * 1120];   // per wave: part[16][68] + ids[16] + wbuf[16]
    float* part = lds + (threadIdx.x >> 6) * 1120;
    int*   ids  = (int*)(part + 16 * 68);
    float* wbuf = (float*)(ids + 16);

    const int wid  = (blockIdx.x * blockDim.x + threadIdx.x) >> 6;
    const int lane = threadIdx.x & 63;
    if (wid >= n) return;

    const int l2   = 2 * lane;
    const bool has2 = (lane < 22);
    const int t16  = lane & 15;
    const int q    = lane >> 4;
    const int byteoff = lane * 4;

    // xr row (f16 pairs)
    const _Float16* xrrow = xrh + (size_t)wid * C_DIM;
    h2 xr0 = *(const h2*)(xrrow + l2);
    h2 xr1 = *(const h2*)(xrrow + 128 + l2);
    h2 xr2 = {(_Float16)0, (_Float16)0};
    if (has2) xr2 = *(const h2*)(xrrow + 256 + l2);

    // 0.6*att / 0.4*att in f16 pairs
    h2 a06[3], a04[3];
    #pragma unroll
    for (int k = 0; k < 3; ++k) {
        int c = 128 * k + l2;
        float ax = (c < C_DIM) ? att[c] : 0.f;
        float ay = (c + 1 < C_DIM) ? att[c + 1] : 0.f;
        a06[k].x = (_Float16)(0.6f * ax); a06[k].y = (_Float16)(0.6f * ay);
        a04[k].x = (_Float16)(0.4f * ax); a04[k].y = (_Float16)(0.4f * ay);
    }

    float acc[6] = {0.f, 0.f, 0.f, 0.f, 0.f, 0.f};
    float den = 0.f;

    const unsigned start = offs[wid];
    const int totalE = (int)(offs[wid + 1] - start) + 1;   // + self loop (k==0)
    const char* basep = (const char*)xlh;

    for (int base = 0; base < totalE; base += CH) {
        // stage the 16 row byte-offsets
        if (lane < CH) {
            int k = base + lane;
            int id = wid;                                   // self-loop & tail filler
            if (k > 0 && k < totalE) id = csr_src[start + k - 1];
            ids[lane] = id * (C_DIM * 2);                   // byte offset
        }
        int rowoff[CH];
        #pragma unroll
        for (int i = 0; i < 4; ++i)
            *(int4*)(rowoff + 4 * i) = *(const int4*)(ids + 4 * i);

        // gather 16 rows (3 dwords per lane each) — all loads independent
        unsigned pk0[CH], pk1[CH], pk2[CH];
        #pragma unroll
        for (int t = 0; t < CH; ++t) {
            const char* p = basep + rowoff[t] + byteoff;
            pk0[t] = *(const unsigned*)(p);
            pk1[t] = *(const unsigned*)(p + 256);
        }
        #pragma unroll
        for (int t = 0; t < CH; ++t) pk2[t] = 0u;
        if (has2) {
            #pragma unroll
            for (int t = 0; t < CH; ++t)
                pk2[t] = *(const unsigned*)(basep + rowoff[t] + byteoff + 512);
        }

        // per-edge per-lane partial logits -> LDS
        #pragma unroll
        for (int t = 0; t < CH; ++t) {
            h2 z0 = as_h2(pk0[t]) + xr0;
            h2 z1 = as_h2(pk1[t]) + xr1;
            h2 z2 = as_h2(pk2[t]) + xr2;
            float p = fdot2w(z0, a06[0], 0.f);
            p = fdot2w(as_h2(as_u(z0) & 0x7FFF7FFFu), a04[0], p);
            p = fdot2w(z1, a06[1], p);
            p = fdot2w(as_h2(as_u(z1) & 0x7FFF7FFFu), a04[1], p);
            p = fdot2w(z2, a06[2], p);
            p = fdot2w(as_h2(as_u(z2) & 0x7FFF7FFFu), a04[2], p);
            part[t * 68 + lane] = p;
        }

        // transpose-reduce: lane sums 16 entries of row t16 (q-rotated to cut conflicts)
        {
            const int qq = (q + t16) & 3;
            const float* rp = part + t16 * 68 + qq * 16;
            float4 s0 = *(const float4*)(rp + 0);
            float4 s1 = *(const float4*)(rp + 4);
            float4 s2 = *(const float4*)(rp + 8);
            float4 s3 = *(const float4*)(rp + 12);
            float e = (((s0.x + s0.y) + (s0.z + s0.w)) + ((s1.x + s1.y) + (s1.z + s1.w)))
                    + (((s2.x + s2.y) + (s2.z + s2.w)) + ((s3.x + s3.y) + (s3.z + s3.w)));
            e += __shfl_xor(e, 16);
            e += __shfl_xor(e, 32);
            bool valid = (base + t16) < totalE;
            float w = valid ? __expf(fminf(e, 60.f)) : 0.f;
            if (lane < CH) wbuf[lane] = w;
        }

        // broadcast weights, accumulate (rows still in registers)
        float wr[CH];
        #pragma unroll
        for (int i = 0; i < 4; ++i)
            *(float4*)(wr + 4 * i) = *(const float4*)(wbuf + 4 * i);

        #pragma unroll
        for (int t = 0; t < CH; ++t) {
            float wt = wr[t];
            den += wt;
            float2 f0 = up2(pk0[t]);
            float2 f1 = up2(pk1[t]);
            float2 f2 = up2(pk2[t]);
            acc[0] = fmaf(wt, f0.x, acc[0]);
            acc[1] = fmaf(wt, f0.y, acc[1]);
            acc[2] = fmaf(wt, f1.x, acc[2]);
            acc[3] = fmaf(wt, f1.y, acc[3]);
            acc[4] = fmaf(wt, f2.x, acc[4]);
            acc[5] = fmaf(wt, f2.y, acc[5]);
        }
    }

    // epilogue: normalize, +bias, relu, dot lw, sigmoid
    const float invd = 1.f / den;
    float dot = 0.f;
    #pragma unroll
    for (int k = 0; k < 3; ++k)
        #pragma unroll
        for (int j = 0; j < 2; ++j) {
            int c = 128 * k + l2 + j;
            float b = (c < C_DIM) ? bias[c] : 0.f;
            float l = (c < C_DIM) ? lw[c] : 0.f;
            float h = fmaf(acc[2 * k + j], invd, b);
            h = h > 0.f ? h : 0.f;
            dot = fmaf(h, l, dot);
        }
    #pragma unroll
    for (int off = 32; off; off >>= 1) dot += __shfl_xor(dot, off);
    if (lane == 0) y[wid] = 1.f / (1.f + __expf(-(dot + lb[0])));
}

extern "C" void kernel_launch(void* const* d_in, const int* in_sizes, int n_in,
                              void* d_out, int out_size, void* d_ws, size_t ws_size,
                              hipStream_t stream)
{
    const float* x    = (const float*)d_in[0];
    const int*   ei   = (const int*)d_in[1];
    const float* Wl   = (const float*)d_in[2];
    const float* bl   = (const float*)d_in[3];
    const float* Wr   = (const float*)d_in[4];
    const float* br   = (const float*)d_in[5];
    const float* att  = (const float*)d_in[6];
    const float* bias = (const float*)d_in[7];
    const float* lw   = (const float*)d_in[8];
    const float* lb   = (const float*)d_in[9];
    float* y = (float*)d_out;

    const int n  = in_sizes[0] / F_IN;   // 50000
    const int nE = in_sizes[1] / 2;      // 800000
    const int* src_arr = ei;
    const int* dst_arr = ei + nE;

    // ws: xlh | xrh | Bp | counts | offs(n+1) | cursor | csr_src
    _Float16* xlh     = (_Float16*)d_ws;
    _Float16* xrh     = xlh + (size_t)n * C_DIM;
    _Float16* Bp      = xrh + (size_t)n * C_DIM;
    unsigned* counts  = (unsigned*)(Bp + NCT * 4 * 64 * 8);
    unsigned* offs    = counts + n;
    unsigned* cursor  = offs + (n + 1);
    int*      csr_src = (int*)(cursor + n);

    convert_w<<<(NCT * 4 * 64 * 8 + 255) / 256, 256, 0, stream>>>(Wl, Wr, Bp);
    hipMemsetAsync(counts, 0, (size_t)n * sizeof(unsigned), stream);
    hist_kernel<<<(nE + 255) / 256, 256, 0, stream>>>(dst_arr, counts, nE);
    scan_kernel<<<1, 1024, 0, stream>>>(counts, offs, cursor, n);
    scatter_csr<<<(nE + 255) / 256, 256, 0, stream>>>(src_arr, dst_arr, cursor, csr_src, nE);

    dim3 g1(NPAD / 64 + 1, (n + 63) / 64);
    gemm_xlxr<<<g1, 256, 0, stream>>>(x, Bp, bl, br, xlh, xrh, n);

    gat_gather<<<(n + 3) / 4, 256, 0, stream>>>(csr_src, offs, xlh, xrh, att, bias, lw, lb, y, n);
}

// Round 6
// 342.846 us; speedup vs baseline: 4.7301x; 1.2796x over previous
//
#include <hip/hip_runtime.h>
#include <hip/hip_fp16.h>

#define F_IN 128
#define C_DIM 300
#define NEG_SLOPE 0.2f
#define NPAD 608          // 2*304: Wl cols [0,300), pad, Wr cols [304,604), pad
#define NCT  40           // padded col-tile count for Bp
#define CH   16           // edges per chunk in gat_gather

typedef _Float16 half8 __attribute__((ext_vector_type(8)));
typedef _Float16 half4 __attribute__((ext_vector_type(4)));
typedef _Float16 h2    __attribute__((ext_vector_type(2)));
typedef float    f32x4 __attribute__((ext_vector_type(4)));

__device__ inline float2 up2(unsigned u) {
    __half2 h;
    *reinterpret_cast<unsigned*>(&h) = u;
    return __half22float2(h);
}
__device__ inline h2 as_h2(unsigned u) { union { unsigned u; h2 h; } c; c.u = u; return c.h; }
__device__ inline unsigned as_u(h2 h)  { union { unsigned u; h2 h; } c; c.h = h; return c.u; }

#if __has_builtin(__builtin_amdgcn_fdot2)
__device__ inline float fdot2w(h2 a, h2 b, float c) {
    return __builtin_amdgcn_fdot2(a, b, c, false);
}
#else
__device__ inline float fdot2w(h2 a, h2 b, float c) {
    return fmaf((float)a.y, (float)b.y, fmaf((float)a.x, (float)b.x, c));
}
#endif

// ---------- K0: build fragment-ready f16 weight layout ----------
__global__ __launch_bounds__(256) void convert_w(
    const float* __restrict__ Wl, const float* __restrict__ Wr,
    _Float16* __restrict__ Bp)
{
    int idx = blockIdx.x * 256 + threadIdx.x;
    if (idx >= NCT * 4 * 64 * 8) return;
    int j    = idx & 7;
    int lane = (idx >> 3) & 63;
    int kc   = idx >> 9;
    int ks   = kc & 3;
    int ct   = kc >> 2;
    int nn   = ct * 16 + (lane & 15);
    int k    = ks * 32 + (lane >> 4) * 8 + j;
    float v = 0.f;
    if (nn < 300)                   v = Wl[(size_t)k * C_DIM + nn];
    else if (nn >= 304 && nn < 604) v = Wr[(size_t)k * C_DIM + (nn - 304)];
    Bp[idx] = (_Float16)v;
}

// ---------- K1: dual GEMM via f16 MFMA; writes f16 tables ----------
__global__ __launch_bounds__(256) void gemm_xlxr(
    const float* __restrict__ x, const _Float16* __restrict__ Bp,
    const float* __restrict__ bl, const float* __restrict__ br,
    _Float16* __restrict__ xlh, _Float16* __restrict__ xrh, int n)
{
    __shared__ __align__(16) _Float16 xs[64][136];
    const int rb0 = blockIdx.y * 64;
    const int nb0 = blockIdx.x * 64;
    const int t   = threadIdx.x;

    #pragma unroll
    for (int i = 0; i < 8; ++i) {
        int flat = (i * 256 + t) * 4;
        int r = flat >> 7;
        int k = flat & 127;
        int gr = rb0 + r;
        if (gr >= n) gr = n - 1;
        float4 v = *reinterpret_cast<const float4*>(x + (size_t)gr * F_IN + k);
        half4 h = { (_Float16)v.x, (_Float16)v.y, (_Float16)v.z, (_Float16)v.w };
        *reinterpret_cast<half4*>(&xs[r][k]) = h;
    }
    __syncthreads();

    const int w    = t >> 6;
    const int lane = t & 63;
    const int m    = lane & 15;
    const int quad = lane >> 4;

    f32x4 acc[4] = {{0,0,0,0},{0,0,0,0},{0,0,0,0},{0,0,0,0}};

    #pragma unroll
    for (int ks = 0; ks < 4; ++ks) {
        half8 a = *reinterpret_cast<const half8*>(&xs[w * 16 + m][ks * 32 + quad * 8]);
        #pragma unroll
        for (int cf = 0; cf < 4; ++cf) {
            int ct = (nb0 >> 4) + cf;
            half8 b = *reinterpret_cast<const half8*>(
                Bp + (((size_t)(ct * 4 + ks) * 64 + lane) << 3));
            acc[cf] = __builtin_amdgcn_mfma_f32_16x16x32_f16(a, b, acc[cf], 0, 0, 0);
        }
    }

    #pragma unroll
    for (int cf = 0; cf < 4; ++cf) {
        int col = nb0 + cf * 16 + m;
        float bv = 0.f;
        int isL = (col < 300);
        int isR = (col >= 304 && col < 604);
        if (isL) bv = bl[col];
        else if (isR) bv = br[col - 304];
        #pragma unroll
        for (int reg = 0; reg < 4; ++reg) {
            int row = rb0 + w * 16 + quad * 4 + reg;
            if (row < n) {
                _Float16 hv = (_Float16)(acc[cf][reg] + bv);
                if (isL)      xlh[(size_t)row * C_DIM + col] = hv;
                else if (isR) xrh[(size_t)row * C_DIM + (col - 304)] = hv;
            }
        }
    }
}

// ---------- CSR build ----------
__global__ __launch_bounds__(256) void hist_kernel(
    const int* __restrict__ dst, unsigned* __restrict__ counts, int nE)
{
    int j = blockIdx.x * blockDim.x + threadIdx.x;
    if (j < nE) atomicAdd(counts + dst[j], 1u);
}

// ---- 3-phase multi-block exclusive scan (1024 counts per block) ----
__global__ __launch_bounds__(256) void scan_part(
    const unsigned* __restrict__ counts, unsigned* __restrict__ bsum, int n)
{
    __shared__ unsigned s[256];
    const int t = threadIdx.x;
    const int base = blockIdx.x * 1024 + t * 4;
    unsigned v = 0;
    #pragma unroll
    for (int i = 0; i < 4; ++i) {
        int idx = base + i;
        if (idx < n) v += counts[idx];
    }
    s[t] = v;
    __syncthreads();
    for (int off = 128; off > 0; off >>= 1) {
        if (t < off) s[t] += s[t + off];
        __syncthreads();
    }
    if (t == 0) bsum[blockIdx.x] = s[0];
}

// one wave scans <=64 block sums -> exclusive bases; writes offs[n]=total
__global__ __launch_bounds__(64) void scan_mid(
    unsigned* __restrict__ bsum, unsigned* __restrict__ offs, int nblk, int n)
{
    const int lane = threadIdx.x;
    unsigned v = (lane < nblk) ? bsum[lane] : 0u;
    unsigned inc = v;
    #pragma unroll
    for (int off = 1; off < 64; off <<= 1) {
        unsigned u = __shfl_up(inc, off);
        if (lane >= off) inc += u;
    }
    if (lane < nblk) bsum[lane] = inc - v;       // exclusive base per block
    if (lane == 63) offs[n] = inc;               // grand total
}

__global__ __launch_bounds__(256) void scan_final(
    const unsigned* __restrict__ counts, const unsigned* __restrict__ bsum,
    unsigned* __restrict__ offs, unsigned* __restrict__ cursor, int n)
{
    __shared__ unsigned s[256];
    const int t = threadIdx.x;
    const int base = blockIdx.x * 1024 + t * 4;
    unsigned c[4];
    unsigned v = 0;
    #pragma unroll
    for (int i = 0; i < 4; ++i) {
        int idx = base + i;
        c[i] = (idx < n) ? counts[idx] : 0u;
        v += c[i];
    }
    s[t] = v;
    __syncthreads();
    for (int off = 1; off < 256; off <<= 1) {
        unsigned u = (t >= off) ? s[t - off] : 0u;
        __syncthreads();
        if (t >= off) s[t] += u;
        __syncthreads();
    }
    unsigned run = bsum[blockIdx.x] + s[t] - v;  // exclusive prefix for first elem
    #pragma unroll
    for (int i = 0; i < 4; ++i) {
        int idx = base + i;
        if (idx < n) {
            offs[idx] = run;
            cursor[idx] = run;
            run += c[i];
        }
    }
}

__global__ __launch_bounds__(256) void scatter_csr(
    const int* __restrict__ src, const int* __restrict__ dst,
    unsigned* __restrict__ cursor, int* __restrict__ csr_src, int nE)
{
    int j = blockIdx.x * blockDim.x + threadIdx.x;
    if (j < nE) {
        unsigned p = atomicAdd(cursor + dst[j], 1u);
        csr_src[p] = src[j];
    }
}

// ---------- K2: fused per-node gather, chunked softmax (16 edges/iter) ----------
__global__ __launch_bounds__(256) void gat_gather(
    const int* __restrict__ csr_src, const unsigned* __restrict__ offs,
    const _Float16* __restrict__ xlh, const _Float16* __restrict__ xrh,
    const float* __restrict__ att, const float* __restrict__ bias,
    const float* __restrict__ lw, const float* __restrict__ lb,
    float* __restrict__ y, int n)
{
    __shared__ __align__(16) float lds[4 * 1120];   // per wave: part[16][68] + ids[16] + wbuf[16]
    float* part = lds + (threadIdx.x >> 6) * 1120;
    int*   ids  = (int*)(part + 16 * 68);
    float* wbuf = (float*)(ids + 16);

    const int wid  = (blockIdx.x * blockDim.x + threadIdx.x) >> 6;
    const int lane = threadIdx.x & 63;
    if (wid >= n) return;

    const int l2   = 2 * lane;
    const bool has2 = (lane < 22);
    const int t16  = lane & 15;
    const int q    = lane >> 4;
    const int byteoff = lane * 4;

    const _Float16* xrrow = xrh + (size_t)wid * C_DIM;
    h2 xr0 = *(const h2*)(xrrow + l2);
    h2 xr1 = *(const h2*)(xrrow + 128 + l2);
    h2 xr2 = {(_Float16)0, (_Float16)0};
    if (has2) xr2 = *(const h2*)(xrrow + 256 + l2);

    h2 a06[3], a04[3];
    #pragma unroll
    for (int k = 0; k < 3; ++k) {
        int c = 128 * k + l2;
        float ax = (c < C_DIM) ? att[c] : 0.f;
        float ay = (c + 1 < C_DIM) ? att[c + 1] : 0.f;
        a06[k].x = (_Float16)(0.6f * ax); a06[k].y = (_Float16)(0.6f * ay);
        a04[k].x = (_Float16)(0.4f * ax); a04[k].y = (_Float16)(0.4f * ay);
    }

    float acc[6] = {0.f, 0.f, 0.f, 0.f, 0.f, 0.f};
    float den = 0.f;

    const unsigned start = offs[wid];
    const int totalE = (int)(offs[wid + 1] - start) + 1;   // + self loop
    const char* basep = (const char*)xlh;

    for (int base = 0; base < totalE; base += CH) {
        if (lane < CH) {
            int k = base + lane;
            int id = wid;
            if (k > 0 && k < totalE) id = csr_src[start + k - 1];
            ids[lane] = id * (C_DIM * 2);
        }
        int rowoff[CH];
        #pragma unroll
        for (int i = 0; i < 4; ++i)
            *(int4*)(rowoff + 4 * i) = *(const int4*)(ids + 4 * i);

        unsigned pk0[CH], pk1[CH], pk2[CH];
        #pragma unroll
        for (int t = 0; t < CH; ++t) {
            const char* p = basep + rowoff[t] + byteoff;
            pk0[t] = *(const unsigned*)(p);
            pk1[t] = *(const unsigned*)(p + 256);
        }
        #pragma unroll
        for (int t = 0; t < CH; ++t) pk2[t] = 0u;
        if (has2) {
            #pragma unroll
            for (int t = 0; t < CH; ++t)
                pk2[t] = *(const unsigned*)(basep + rowoff[t] + byteoff + 512);
        }

        #pragma unroll
        for (int t = 0; t < CH; ++t) {
            h2 z0 = as_h2(pk0[t]) + xr0;
            h2 z1 = as_h2(pk1[t]) + xr1;
            h2 z2 = as_h2(pk2[t]) + xr2;
            float p = fdot2w(z0, a06[0], 0.f);
            p = fdot2w(as_h2(as_u(z0) & 0x7FFF7FFFu), a04[0], p);
            p = fdot2w(z1, a06[1], p);
            p = fdot2w(as_h2(as_u(z1) & 0x7FFF7FFFu), a04[1], p);
            p = fdot2w(z2, a06[2], p);
            p = fdot2w(as_h2(as_u(z2) & 0x7FFF7FFFu), a04[2], p);
            part[t * 68 + lane] = p;
        }

        {
            const int qq = (q + t16) & 3;
            const float* rp = part + t16 * 68 + qq * 16;
            float4 s0 = *(const float4*)(rp + 0);
            float4 s1 = *(const float4*)(rp + 4);
            float4 s2 = *(const float4*)(rp + 8);
            float4 s3 = *(const float4*)(rp + 12);
            float e = (((s0.x + s0.y) + (s0.z + s0.w)) + ((s1.x + s1.y) + (s1.z + s1.w)))
                    + (((s2.x + s2.y) + (s2.z + s2.w)) + ((s3.x + s3.y) + (s3.z + s3.w)));
            e += __shfl_xor(e, 16);
            e += __shfl_xor(e, 32);
            bool valid = (base + t16) < totalE;
            float w = valid ? __expf(fminf(e, 60.f)) : 0.f;
            if (lane < CH) wbuf[lane] = w;
        }

        float wr[CH];
        #pragma unroll
        for (int i = 0; i < 4; ++i)
            *(float4*)(wr + 4 * i) = *(const float4*)(wbuf + 4 * i);

        #pragma unroll
        for (int t = 0; t < CH; ++t) {
            float wt = wr[t];
            den += wt;
            float2 f0 = up2(pk0[t]);
            float2 f1 = up2(pk1[t]);
            float2 f2 = up2(pk2[t]);
            acc[0] = fmaf(wt, f0.x, acc[0]);
            acc[1] = fmaf(wt, f0.y, acc[1]);
            acc[2] = fmaf(wt, f1.x, acc[2]);
            acc[3] = fmaf(wt, f1.y, acc[3]);
            acc[4] = fmaf(wt, f2.x, acc[4]);
            acc[5] = fmaf(wt, f2.y, acc[5]);
        }
    }

    const float invd = 1.f / den;
    float dot = 0.f;
    #pragma unroll
    for (int k = 0; k < 3; ++k)
        #pragma unroll
        for (int j = 0; j < 2; ++j) {
            int c = 128 * k + l2 + j;
            float b = (c < C_DIM) ? bias[c] : 0.f;
            float l = (c < C_DIM) ? lw[c] : 0.f;
            float h = fmaf(acc[2 * k + j], invd, b);
            h = h > 0.f ? h : 0.f;
            dot = fmaf(h, l, dot);
        }
    #pragma unroll
    for (int off = 32; off; off >>= 1) dot += __shfl_xor(dot, off);
    if (lane == 0) y[wid] = 1.f / (1.f + __expf(-(dot + lb[0])));
}

extern "C" void kernel_launch(void* const* d_in, const int* in_sizes, int n_in,
                              void* d_out, int out_size, void* d_ws, size_t ws_size,
                              hipStream_t stream)
{
    const float* x    = (const float*)d_in[0];
    const int*   ei   = (const int*)d_in[1];
    const float* Wl   = (const float*)d_in[2];
    const float* bl   = (const float*)d_in[3];
    const float* Wr   = (const float*)d_in[4];
    const float* br   = (const float*)d_in[5];
    const float* att  = (const float*)d_in[6];
    const float* bias = (const float*)d_in[7];
    const float* lw   = (const float*)d_in[8];
    const float* lb   = (const float*)d_in[9];
    float* y = (float*)d_out;

    const int n  = in_sizes[0] / F_IN;   // 50000
    const int nE = in_sizes[1] / 2;      // 800000
    const int* src_arr = ei;
    const int* dst_arr = ei + nE;
    const int nblk = (n + 1023) / 1024;  // 49 <= 64

    // ws: xlh | xrh | Bp | counts | offs(n+1) | cursor | bsum(64) | csr_src
    _Float16* xlh     = (_Float16*)d_ws;
    _Float16* xrh     = xlh + (size_t)n * C_DIM;
    _Float16* Bp      = xrh + (size_t)n * C_DIM;
    unsigned* counts  = (unsigned*)(Bp + NCT * 4 * 64 * 8);
    unsigned* offs    = counts + n;
    unsigned* cursor  = offs + (n + 1);
    unsigned* bsum    = cursor + n;
    int*      csr_src = (int*)(bsum + 64);

    convert_w<<<(NCT * 4 * 64 * 8 + 255) / 256, 256, 0, stream>>>(Wl, Wr, Bp);
    hipMemsetAsync(counts, 0, (size_t)n * sizeof(unsigned), stream);
    hist_kernel<<<(nE + 255) / 256, 256, 0, stream>>>(dst_arr, counts, nE);
    scan_part<<<nblk, 256, 0, stream>>>(counts, bsum, n);
    scan_mid<<<1, 64, 0, stream>>>(bsum, offs, nblk, n);
    scan_final<<<nblk, 256, 0, stream>>>(counts, bsum, offs, cursor, n);
    scatter_csr<<<(nE + 255) / 256, 256, 0, stream>>>(src_arr, dst_arr, cursor, csr_src, nE);

    dim3 g1(NPAD / 64 + 1, (n + 63) / 64);
    gemm_xlxr<<<g1, 256, 0, stream>>>(x, Bp, bl, br, xlh, xrh, n);

    gat_gather<<<(n + 3) / 4, 256, 0, stream>>>(csr_src, offs, xlh, xrh, att, bias, lw, lb, y, n);
}

// Round 7
// 314.646 us; speedup vs baseline: 5.1541x; 1.0896x over previous
//
#include <hip/hip_runtime.h>
#include <hip/hip_fp16.h>

#define F_IN 128
#define C_DIM 300
#define NEG_SLOPE 0.2f
#define NCT  40           // col-tile count for Bp (640 padded cols)
#define CH   8            // edges per chunk in gat_gather

typedef _Float16 half8 __attribute__((ext_vector_type(8)));
typedef _Float16 half4 __attribute__((ext_vector_type(4)));
typedef _Float16 h2    __attribute__((ext_vector_type(2)));
typedef float    f32x4 __attribute__((ext_vector_type(4)));
typedef float    f32x2 __attribute__((ext_vector_type(2)));

__device__ inline h2 as_h2(unsigned u) { union { unsigned u; h2 h; } c; c.u = u; return c.h; }
__device__ inline unsigned as_u(h2 h)  { union { unsigned u; h2 h; } c; c.h = h; return c.u; }
__device__ inline f32x2 upv(unsigned u) {
    h2 h = as_h2(u);
    f32x2 r; r.x = (float)h.x; r.y = (float)h.y; return r;
}
__device__ inline f32x2 fma2(f32x2 a, f32x2 b, f32x2 c) {
#if __has_builtin(__builtin_elementwise_fma)
    return __builtin_elementwise_fma(a, b, c);
#else
    f32x2 r; r.x = fmaf(a.x, b.x, c.x); r.y = fmaf(a.y, b.y, c.y); return r;
#endif
}

#if __has_builtin(__builtin_amdgcn_fdot2)
__device__ inline float fdot2w(h2 a, h2 b, float c) {
    return __builtin_amdgcn_fdot2(a, b, c, false);
}
#else
__device__ inline float fdot2w(h2 a, h2 b, float c) {
    return fmaf((float)a.y, (float)b.y, fmaf((float)a.x, (float)b.x, c));
}
#endif

// ---------- K0: build fragment-ready f16 weight layout (coalesced reads) ----------
// Bp[((ct*4+ks)*64+lane)*8+j] = Wcat[k][nn], nn=ct*16+(lane&15), k=ks*32+(lane>>4)*8+j
__global__ __launch_bounds__(256) void convert_w(
    const float* __restrict__ Wl, const float* __restrict__ Wr,
    _Float16* __restrict__ Bp)
{
    int idx = blockIdx.x * 256 + threadIdx.x;        // 0 .. 640*128-1
    if (idx >= 640 * F_IN) return;
    int nn = idx % 640;                               // fastest -> coalesced W reads
    int k  = idx / 640;
    float v = 0.f;
    if (nn < 300)                   v = Wl[k * C_DIM + nn];
    else if (nn >= 304 && nn < 604) v = Wr[k * C_DIM + (nn - 304)];
    int ct = nn >> 4, n16 = nn & 15;
    int kr = k & 31,  ks  = k >> 5;
    int lane = ((kr >> 3) << 4) | n16;
    int j = k & 7;
    Bp[((((ct * 4 + ks) * 64) + lane) << 3) | j] = (_Float16)v;
}

// ---------- K1: dual GEMM via f16 MFMA; 782 blocks, wave sweeps all 40 col-tiles ----------
__global__ __launch_bounds__(256) void gemm_xlxr(
    const float* __restrict__ x, const _Float16* __restrict__ Bp,
    const float* __restrict__ bl, const float* __restrict__ br,
    _Float16* __restrict__ xlh, _Float16* __restrict__ xrh, int n)
{
    __shared__ __align__(16) _Float16 xs[64][136];
    const int rb0 = blockIdx.x * 64;
    const int t   = threadIdx.x;

    #pragma unroll
    for (int i = 0; i < 8; ++i) {
        int flat = (i * 256 + t) * 4;
        int r = flat >> 7;
        int k = flat & 127;
        int gr = rb0 + r;
        if (gr >= n) gr = n - 1;
        float4 v = *reinterpret_cast<const float4*>(x + (size_t)gr * F_IN + k);
        half4 h = { (_Float16)v.x, (_Float16)v.y, (_Float16)v.z, (_Float16)v.w };
        *reinterpret_cast<half4*>(&xs[r][k]) = h;
    }
    __syncthreads();

    const int w    = t >> 6;
    const int lane = t & 63;
    const int m    = lane & 15;
    const int quad = lane >> 4;

    // A-fragments for this wave's 16 rows, all 4 K-steps, kept in regs
    half8 a[4];
    #pragma unroll
    for (int ks = 0; ks < 4; ++ks)
        a[ks] = *reinterpret_cast<const half8*>(&xs[w * 16 + m][ks * 32 + quad * 8]);

    const int rbase = rb0 + w * 16 + quad * 4;

    #pragma unroll 4
    for (int ct = 0; ct < NCT; ++ct) {
        f32x4 acc = {0.f, 0.f, 0.f, 0.f};
        #pragma unroll
        for (int ks = 0; ks < 4; ++ks) {
            half8 b = *reinterpret_cast<const half8*>(
                Bp + (((size_t)(ct * 4 + ks) * 64 + lane) << 3));
            acc = __builtin_amdgcn_mfma_f32_16x16x32_f16(a[ks], b, acc, 0, 0, 0);
        }
        int col = ct * 16 + m;
        int isL = (col < 300);
        int isR = (col >= 304 && col < 604);
        if (isL | isR) {
            float bv = isL ? bl[col] : br[col - 304];
            _Float16* tab = isL ? (xlh + col) : (xrh + (col - 304));
            #pragma unroll
            for (int reg = 0; reg < 4; ++reg) {
                int row = rbase + reg;
                if (row < n)
                    tab[(size_t)row * C_DIM] = (_Float16)(acc[reg] + bv);
            }
        }
    }
}

// ---------- CSR build ----------
__global__ __launch_bounds__(256) void hist_kernel(
    const int* __restrict__ dst, unsigned* __restrict__ counts, int nE)
{
    int j = blockIdx.x * blockDim.x + threadIdx.x;
    if (j < nE) atomicAdd(counts + dst[j], 1u);
}

__global__ __launch_bounds__(256) void scan_part(
    const unsigned* __restrict__ counts, unsigned* __restrict__ bsum, int n)
{
    __shared__ unsigned s[256];
    const int t = threadIdx.x;
    const int base = blockIdx.x * 1024 + t * 4;
    unsigned v = 0;
    #pragma unroll
    for (int i = 0; i < 4; ++i) {
        int idx = base + i;
        if (idx < n) v += counts[idx];
    }
    s[t] = v;
    __syncthreads();
    for (int off = 128; off > 0; off >>= 1) {
        if (t < off) s[t] += s[t + off];
        __syncthreads();
    }
    if (t == 0) bsum[blockIdx.x] = s[0];
}

__global__ __launch_bounds__(64) void scan_mid(
    unsigned* __restrict__ bsum, unsigned* __restrict__ offs, int nblk, int n)
{
    const int lane = threadIdx.x;
    unsigned v = (lane < nblk) ? bsum[lane] : 0u;
    unsigned inc = v;
    #pragma unroll
    for (int off = 1; off < 64; off <<= 1) {
        unsigned u = __shfl_up(inc, off);
        if (lane >= off) inc += u;
    }
    if (lane < nblk) bsum[lane] = inc - v;
    if (lane == 63) offs[n] = inc;
}

__global__ __launch_bounds__(256) void scan_final(
    const unsigned* __restrict__ counts, const unsigned* __restrict__ bsum,
    unsigned* __restrict__ offs, unsigned* __restrict__ cursor, int n)
{
    __shared__ unsigned s[256];
    const int t = threadIdx.x;
    const int base = blockIdx.x * 1024 + t * 4;
    unsigned c[4];
    unsigned v = 0;
    #pragma unroll
    for (int i = 0; i < 4; ++i) {
        int idx = base + i;
        c[i] = (idx < n) ? counts[idx] : 0u;
        v += c[i];
    }
    s[t] = v;
    __syncthreads();
    for (int off = 1; off < 256; off <<= 1) {
        unsigned u = (t >= off) ? s[t - off] : 0u;
        __syncthreads();
        if (t >= off) s[t] += u;
        __syncthreads();
    }
    unsigned run = bsum[blockIdx.x] + s[t] - v;
    #pragma unroll
    for (int i = 0; i < 4; ++i) {
        int idx = base + i;
        if (idx < n) {
            offs[idx] = run;
            cursor[idx] = run;
            run += c[i];
        }
    }
}

__global__ __launch_bounds__(256) void scatter_csr(
    const int* __restrict__ src, const int* __restrict__ dst,
    unsigned* __restrict__ cursor, int* __restrict__ csr_src, int nE)
{
    int j = blockIdx.x * blockDim.x + threadIdx.x;
    if (j < nE) {
        unsigned p = atomicAdd(cursor + dst[j], 1u);
        csr_src[p] = src[j];
    }
}

// ---------- K2: fused per-node gather, chunked softmax (8 edges/iter) ----------
// one wave per node; lane owns channels c = 128k + 2*lane + j
// leaky(z).att == dot(z,0.6att) + dot(|z|,0.4att)   (slope 0.2)
__global__ __launch_bounds__(256) void gat_gather(
    const int* __restrict__ csr_src, const unsigned* __restrict__ offs,
    const _Float16* __restrict__ xlh, const _Float16* __restrict__ xrh,
    const float* __restrict__ att, const float* __restrict__ bias,
    const float* __restrict__ lw, const float* __restrict__ lb,
    float* __restrict__ y, int n)
{
    __shared__ __align__(16) float lds[4 * 560];   // per wave: part[8][68]
    float* part = lds + (threadIdx.x >> 6) * 560;

    const int wid  = (blockIdx.x * blockDim.x + threadIdx.x) >> 6;
    const int lane = threadIdx.x & 63;
    if (wid >= n) return;

    const int l2   = 2 * lane;
    const bool has2 = (lane < 22);
    const int t8   = lane & 7;
    const int o    = lane >> 3;
    const int byteoff = lane * 4;

    const _Float16* xrrow = xrh + (size_t)wid * C_DIM;
    h2 xr0 = *(const h2*)(xrrow + l2);
    h2 xr1 = *(const h2*)(xrrow + 128 + l2);
    h2 xr2 = {(_Float16)0, (_Float16)0};
    if (has2) xr2 = *(const h2*)(xrrow + 256 + l2);

    h2 a06[3], a04[3];
    #pragma unroll
    for (int k = 0; k < 3; ++k) {
        int c = 128 * k + l2;
        float ax = (c < C_DIM) ? att[c] : 0.f;
        float ay = (c + 1 < C_DIM) ? att[c + 1] : 0.f;
        a06[k].x = (_Float16)(0.6f * ax); a06[k].y = (_Float16)(0.6f * ay);
        a04[k].x = (_Float16)(0.4f * ax); a04[k].y = (_Float16)(0.4f * ay);
    }

    f32x2 acc2[3] = {{0.f, 0.f}, {0.f, 0.f}, {0.f, 0.f}};
    float den = 0.f;

    const unsigned start = offs[wid];
    const int totalE = (int)(offs[wid + 1] - start) + 1;   // + self loop (k==0)
    const char* basep = (const char*)xlh;

    for (int base = 0; base < totalE; base += CH) {
        // lane tt (<8) owns edge base+tt; broadcast row byte-offsets by shuffle
        int idv = wid;                                      // self-loop & filler
        {
            int k = base + lane;
            if (lane < CH && k > 0 && k < totalE) idv = csr_src[start + k - 1];
        }
        int rowb = idv * (C_DIM * 2);
        int ro[CH];
        #pragma unroll
        for (int tt = 0; tt < CH; ++tt) ro[tt] = __shfl(rowb, tt);

        unsigned pk0[CH], pk1[CH], pk2[CH];
        #pragma unroll
        for (int tt = 0; tt < CH; ++tt) {
            const char* p = basep + ro[tt] + byteoff;
            pk0[tt] = *(const unsigned*)(p);
            pk1[tt] = *(const unsigned*)(p + 256);
            pk2[tt] = 0u;
        }
        if (has2) {
            #pragma unroll
            for (int tt = 0; tt < CH; ++tt)
                pk2[tt] = *(const unsigned*)(basep + ro[tt] + byteoff + 512);
        }

        // per-edge per-lane partial logits -> LDS (wave-local region)
        #pragma unroll
        for (int tt = 0; tt < CH; ++tt) {
            h2 z0 = as_h2(pk0[tt]) + xr0;
            h2 z1 = as_h2(pk1[tt]) + xr1;
            h2 z2 = as_h2(pk2[tt]) + xr2;
            float p = fdot2w(z0, a06[0], 0.f);
            p = fdot2w(as_h2(as_u(z0) & 0x7FFF7FFFu), a04[0], p);
            p = fdot2w(z1, a06[1], p);
            p = fdot2w(as_h2(as_u(z1) & 0x7FFF7FFFu), a04[1], p);
            p = fdot2w(z2, a06[2], p);
            p = fdot2w(as_h2(as_u(z2) & 0x7FFF7FFFu), a04[2], p);
            part[tt * 68 + lane] = p;
        }

        // transpose-reduce: 8 lanes per edge-row, rotated b128 reads
        float wgt;
        {
            const int oo = (o + t8) & 7;
            const float* rp = part + t8 * 68 + oo * 8;
            float4 s0 = *(const float4*)(rp + 0);
            float4 s1 = *(const float4*)(rp + 4);
            float e = ((s0.x + s0.y) + (s0.z + s0.w)) + ((s1.x + s1.y) + (s1.z + s1.w));
            e += __shfl_xor(e, 8);
            e += __shfl_xor(e, 16);
            e += __shfl_xor(e, 32);
            bool valid = (base + t8) < totalE;
            wgt = valid ? __expf(fminf(e, 60.f)) : 0.f;   // lane tt holds edge tt's w
        }

        #pragma unroll
        for (int tt = 0; tt < CH; ++tt) {
            float wt = __shfl(wgt, tt);
            den += wt;
            f32x2 wt2 = {wt, wt};
            acc2[0] = fma2(wt2, upv(pk0[tt]), acc2[0]);
            acc2[1] = fma2(wt2, upv(pk1[tt]), acc2[1]);
            acc2[2] = fma2(wt2, upv(pk2[tt]), acc2[2]);
        }
    }

    const float invd = 1.f / den;
    float dot = 0.f;
    #pragma unroll
    for (int k = 0; k < 3; ++k) {
        #pragma unroll
        for (int j = 0; j < 2; ++j) {
            int c = 128 * k + l2 + j;
            float b = (c < C_DIM) ? bias[c] : 0.f;
            float l = (c < C_DIM) ? lw[c] : 0.f;
            float a = (j == 0) ? acc2[k].x : acc2[k].y;
            float h = fmaf(a, invd, b);
            h = h > 0.f ? h : 0.f;
            dot = fmaf(h, l, dot);
        }
    }
    #pragma unroll
    for (int off = 32; off; off >>= 1) dot += __shfl_xor(dot, off);
    if (lane == 0) y[wid] = 1.f / (1.f + __expf(-(dot + lb[0])));
}

extern "C" void kernel_launch(void* const* d_in, const int* in_sizes, int n_in,
                              void* d_out, int out_size, void* d_ws, size_t ws_size,
                              hipStream_t stream)
{
    const float* x    = (const float*)d_in[0];
    const int*   ei   = (const int*)d_in[1];
    const float* Wl   = (const float*)d_in[2];
    const float* bl   = (const float*)d_in[3];
    const float* Wr   = (const float*)d_in[4];
    const float* br   = (const float*)d_in[5];
    const float* att  = (const float*)d_in[6];
    const float* bias = (const float*)d_in[7];
    const float* lw   = (const float*)d_in[8];
    const float* lb   = (const float*)d_in[9];
    float* y = (float*)d_out;

    const int n  = in_sizes[0] / F_IN;   // 50000
    const int nE = in_sizes[1] / 2;      // 800000
    const int* src_arr = ei;
    const int* dst_arr = ei + nE;
    const int nblk = (n + 1023) / 1024;  // 49 <= 64

    // ws: xlh | xrh | Bp | counts | offs(n+1) | cursor | bsum(64) | csr_src
    _Float16* xlh     = (_Float16*)d_ws;
    _Float16* xrh     = xlh + (size_t)n * C_DIM;
    _Float16* Bp      = xrh + (size_t)n * C_DIM;
    unsigned* counts  = (unsigned*)(Bp + NCT * 4 * 64 * 8);
    unsigned* offs    = counts + n;
    unsigned* cursor  = offs + (n + 1);
    unsigned* bsum    = cursor + n;
    int*      csr_src = (int*)(bsum + 64);

    convert_w<<<(640 * F_IN + 255) / 256, 256, 0, stream>>>(Wl, Wr, Bp);
    hipMemsetAsync(counts, 0, (size_t)n * sizeof(unsigned), stream);
    hist_kernel<<<(nE + 255) / 256, 256, 0, stream>>>(dst_arr, counts, nE);
    scan_part<<<nblk, 256, 0, stream>>>(counts, bsum, n);
    scan_mid<<<1, 64, 0, stream>>>(bsum, offs, nblk, n);
    scan_final<<<nblk, 256, 0, stream>>>(counts, bsum, offs, cursor, n);
    scatter_csr<<<(nE + 255) / 256, 256, 0, stream>>>(src_arr, dst_arr, cursor, csr_src, nE);

    gemm_xlxr<<<(n + 63) / 64, 256, 0, stream>>>(x, Bp, bl, br, xlh, xrh, n);

    gat_gather<<<(n + 3) / 4, 256, 0, stream>>>(csr_src, offs, xlh, xrh, att, bias, lw, lb, y, n);
}